// Round 1
// baseline (222.540 us; speedup 1.0000x reference)
//
#include <hip/hip_runtime.h>

// Problem constants (from reference): text [T,B] int tokens, W [L,V] f32, b [L] f32
// out [B,L] f32.  Multi-hot BOW (dedup per row, skip PAD) @ linear layer.
#define T_TOK 200
#define B_SZ  1024
#define V_SZ  50000
#define L_SZ  512
#define PAD_TOK 1

#define BMW ((V_SZ + 31) / 32)   // bitmap words = 1563

// ---------------------------------------------------------------------------
// Transpose W [L, V] -> Wt [V, L] so per-token gathers become coalesced rows.
// Classic 32x32 LDS tile with +1 pad. Grid: (ceil(V/32), L/32), block (32,8).
// ---------------------------------------------------------------------------
__global__ __launch_bounds__(256) void transpose_W(const float* __restrict__ W,
                                                   float* __restrict__ Wt) {
    __shared__ float tile[32][33];
    const int tx = threadIdx.x;        // 0..31
    const int ty = threadIdx.y;        // 0..7
    const int v0 = blockIdx.x * 32;
    const int l0 = blockIdx.y * 32;    // grid.y*32 == 512 exactly, no l guard
#pragma unroll
    for (int i = 0; i < 32; i += 8) {
        const int v = v0 + tx;
        const int l = l0 + ty + i;
        tile[ty + i][tx] = (v < V_SZ) ? W[(size_t)l * V_SZ + v] : 0.0f;
    }
    __syncthreads();
#pragma unroll
    for (int i = 0; i < 32; i += 8) {
        const int v = v0 + ty + i;
        const int l = l0 + tx;
        if (v < V_SZ) Wt[(size_t)v * L_SZ + l] = tile[tx][ty + i];
    }
}

// ---------------------------------------------------------------------------
// One block per batch row. Dedup tokens via LDS bitmap (atomicOr old-value
// check), then accumulate Wt rows (coalesced float2 per thread).
// 256 threads: thread tid owns out[b, 2*tid .. 2*tid+1].
// ---------------------------------------------------------------------------
__global__ __launch_bounds__(256) void bow_gather(const int* __restrict__ text,
                                                  const float* __restrict__ Wt,
                                                  const float* __restrict__ bias,
                                                  float* __restrict__ out) {
    __shared__ unsigned int bitmap[BMW];
    __shared__ int toklist[T_TOK];
    __shared__ int cnt;

    const int b   = blockIdx.x;
    const int tid = threadIdx.x;

    for (int i = tid; i < BMW; i += 256) bitmap[i] = 0u;
    if (tid == 0) cnt = 0;
    __syncthreads();

    for (int t = tid; t < T_TOK; t += 256) {
        const int tok = text[t * B_SZ + b];
        if (tok != PAD_TOK) {
            const unsigned mask = 1u << (tok & 31);
            const unsigned old  = atomicOr(&bitmap[tok >> 5], mask);
            if (!(old & mask)) {
                const int idx = atomicAdd(&cnt, 1);
                toklist[idx] = tok;
            }
        }
    }
    __syncthreads();

    const int n = cnt;
    const float2* __restrict__ Wt2 = (const float2*)Wt;
    float2 acc = ((const float2*)bias)[tid];
    for (int i = 0; i < n; ++i) {
        const int tok = toklist[i];                 // LDS broadcast
        const float2 w = Wt2[tok * (L_SZ / 2) + tid];
        acc.x += w.x;
        acc.y += w.y;
    }
    ((float2*)out)[b * (L_SZ / 2) + tid] = acc;
}

// ---------------------------------------------------------------------------
// Fallback if workspace is too small for Wt: gather directly from W
// (uncoalesced but correct). Thread tid owns l = tid and l = tid + 256.
// ---------------------------------------------------------------------------
__global__ __launch_bounds__(256) void bow_gather_nt(const int* __restrict__ text,
                                                     const float* __restrict__ W,
                                                     const float* __restrict__ bias,
                                                     float* __restrict__ out) {
    __shared__ unsigned int bitmap[BMW];
    __shared__ int toklist[T_TOK];
    __shared__ int cnt;

    const int b   = blockIdx.x;
    const int tid = threadIdx.x;

    for (int i = tid; i < BMW; i += 256) bitmap[i] = 0u;
    if (tid == 0) cnt = 0;
    __syncthreads();

    for (int t = tid; t < T_TOK; t += 256) {
        const int tok = text[t * B_SZ + b];
        if (tok != PAD_TOK) {
            const unsigned mask = 1u << (tok & 31);
            const unsigned old  = atomicOr(&bitmap[tok >> 5], mask);
            if (!(old & mask)) {
                const int idx = atomicAdd(&cnt, 1);
                toklist[idx] = tok;
            }
        }
    }
    __syncthreads();

    const int n = cnt;
    const int l0 = tid;
    const int l1 = tid + 256;
    float acc0 = bias[l0];
    float acc1 = bias[l1];
    for (int i = 0; i < n; ++i) {
        const int tok = toklist[i];
        acc0 += W[(size_t)l0 * V_SZ + tok];
        acc1 += W[(size_t)l1 * V_SZ + tok];
    }
    out[b * L_SZ + l0] = acc0;
    out[b * L_SZ + l1] = acc1;
}

extern "C" void kernel_launch(void* const* d_in, const int* in_sizes, int n_in,
                              void* d_out, int out_size, void* d_ws, size_t ws_size,
                              hipStream_t stream) {
    const int*   text = (const int*)d_in[0];    // [T, B]
    const float* W    = (const float*)d_in[1];  // [L, V]
    const float* bias = (const float*)d_in[2];  // [L]
    float* out = (float*)d_out;                 // [B, L]

    const size_t need = (size_t)V_SZ * L_SZ * sizeof(float);  // 102.4 MB
    if (ws_size >= need) {
        float* Wt = (float*)d_ws;               // [V, L]
        dim3 tb(32, 8);
        dim3 tg((V_SZ + 31) / 32, L_SZ / 32);   // (1563, 16)
        transpose_W<<<tg, tb, 0, stream>>>(W, Wt);
        bow_gather<<<B_SZ, 256, 0, stream>>>(text, Wt, bias, out);
    } else {
        bow_gather_nt<<<B_SZ, 256, 0, stream>>>(text, W, bias, out);
    }
}

// Round 2
// 194.595 us; speedup vs baseline: 1.1436x; 1.1436x over previous
//
#include <hip/hip_runtime.h>
#include <hip/hip_fp16.h>

// text [T,B] int tokens, W [L,V] f32, b [L] f32, out [B,L] f32.
// Multi-hot BOW (dedup per row, skip PAD) @ linear layer.
#define T_TOK 200
#define B_SZ  1024
#define V_SZ  50000
#define L_SZ  512
#define PAD_TOK 1

#define BMW ((V_SZ + 31) / 32)   // bitmap words = 1563

// ---------------------------------------------------------------------------
// Transpose + downconvert: W [L, V] f32 -> Wt [V, L] f16.
// 128(v) x 128(l) tile in LDS (stride 130 halfs: 2-way-or-free bank pattern).
// Grid: (ceil(V/128), L/128) = (391, 4), block 256.
// ---------------------------------------------------------------------------
#define TT_V 128
#define TT_L 128
#define TT_S 130   // LDS row stride in halfs (l-dim 128 + 2 pad, keeps half2 alignment)

__global__ __launch_bounds__(256) void transpose_W_f16(const float* __restrict__ W,
                                                       __half* __restrict__ Wt) {
    __shared__ __half tile[TT_V * TT_S];   // 33280 B
    const int tid = threadIdx.x;
    const int v0  = blockIdx.x * TT_V;
    const int l0  = blockIdx.y * TT_L;

    // Load phase: thread covers v-quad [4*(tid&31)..+3] at rows l0 + (tid>>5) + 8k.
    const int vq   = 4 * (tid & 31);
    const int lrow = tid >> 5;
#pragma unroll
    for (int k = 0; k < TT_L / 8; ++k) {
        const int lt = lrow + 8 * k;         // 0..127
        const size_t base = (size_t)(l0 + lt) * V_SZ + v0 + vq;
        float4 val;
        if (v0 + vq + 3 < V_SZ) {
            val = *(const float4*)&W[base];
        } else {
            val.x = (v0 + vq + 0 < V_SZ) ? W[base + 0] : 0.0f;
            val.y = (v0 + vq + 1 < V_SZ) ? W[base + 1] : 0.0f;
            val.z = (v0 + vq + 2 < V_SZ) ? W[base + 2] : 0.0f;
            val.w = (v0 + vq + 3 < V_SZ) ? W[base + 3] : 0.0f;
        }
        tile[(vq + 0) * TT_S + lt] = __float2half(val.x);
        tile[(vq + 1) * TT_S + lt] = __float2half(val.y);
        tile[(vq + 2) * TT_S + lt] = __float2half(val.z);
        tile[(vq + 3) * TT_S + lt] = __float2half(val.w);
    }
    __syncthreads();

    // Store phase: group g (of 4) writes v = g + 4k; 64 lanes write half2 -> 256 B/row seg.
    const int lane = tid & 63;
    const int g    = tid >> 6;
#pragma unroll
    for (int k = 0; k < TT_V / 4; ++k) {
        const int v  = g + 4 * k;
        const int vg = v0 + v;
        if (vg < V_SZ) {
            const __half2 h = *(const __half2*)&tile[v * TT_S + 2 * lane];
            *(__half2*)&Wt[(size_t)vg * L_SZ + l0 + 2 * lane] = h;
        }
    }
}

// ---------------------------------------------------------------------------
// One block per batch row. Dedup via LDS bitmap, then accumulate Wt (f16)
// rows. Thread tid owns l = 2*tid, 2*tid+1 (one half2 per token). Token loop
// manually unrolled 8x for 8 independent loads in flight.
// ---------------------------------------------------------------------------
__global__ __launch_bounds__(256) void bow_gather_f16(const int* __restrict__ text,
                                                      const __half2* __restrict__ Wt2,
                                                      const float* __restrict__ bias,
                                                      float* __restrict__ out) {
    __shared__ unsigned int bitmap[BMW];
    __shared__ int toklist[T_TOK];
    __shared__ int cnt;

    const int b   = blockIdx.x;
    const int tid = threadIdx.x;

    for (int i = tid; i < BMW; i += 256) bitmap[i] = 0u;
    if (tid == 0) cnt = 0;
    __syncthreads();

    if (tid < T_TOK) {
        const int tok = text[tid * B_SZ + b];
        if (tok != PAD_TOK) {
            const unsigned mask = 1u << (tok & 31);
            const unsigned old  = atomicOr(&bitmap[tok >> 5], mask);
            if (!(old & mask)) {
                const int idx = atomicAdd(&cnt, 1);
                toklist[idx] = tok;
            }
        }
    }
    __syncthreads();

    const int n = cnt;
    float2 acc = ((const float2*)bias)[tid];

    int i = 0;
    for (; i + 8 <= n; i += 8) {
        const int t0 = toklist[i + 0], t1 = toklist[i + 1];
        const int t2 = toklist[i + 2], t3 = toklist[i + 3];
        const int t4 = toklist[i + 4], t5 = toklist[i + 5];
        const int t6 = toklist[i + 6], t7 = toklist[i + 7];
        const __half2 w0 = Wt2[t0 * (L_SZ / 2) + tid];
        const __half2 w1 = Wt2[t1 * (L_SZ / 2) + tid];
        const __half2 w2 = Wt2[t2 * (L_SZ / 2) + tid];
        const __half2 w3 = Wt2[t3 * (L_SZ / 2) + tid];
        const __half2 w4 = Wt2[t4 * (L_SZ / 2) + tid];
        const __half2 w5 = Wt2[t5 * (L_SZ / 2) + tid];
        const __half2 w6 = Wt2[t6 * (L_SZ / 2) + tid];
        const __half2 w7 = Wt2[t7 * (L_SZ / 2) + tid];
        const float2 f0 = __half22float2(w0), f1 = __half22float2(w1);
        const float2 f2 = __half22float2(w2), f3 = __half22float2(w3);
        const float2 f4 = __half22float2(w4), f5 = __half22float2(w5);
        const float2 f6 = __half22float2(w6), f7 = __half22float2(w7);
        acc.x += f0.x + f1.x + f2.x + f3.x + f4.x + f5.x + f6.x + f7.x;
        acc.y += f0.y + f1.y + f2.y + f3.y + f4.y + f5.y + f6.y + f7.y;
    }
    for (; i < n; ++i) {
        const float2 f = __half22float2(Wt2[toklist[i] * (L_SZ / 2) + tid]);
        acc.x += f.x;
        acc.y += f.y;
    }
    ((float2*)out)[b * (L_SZ / 2) + tid] = acc;
}

// ---------------------------------------------------------------------------
// Fallback if workspace too small: gather directly from W (uncoalesced, slow).
// ---------------------------------------------------------------------------
__global__ __launch_bounds__(256) void bow_gather_nt(const int* __restrict__ text,
                                                     const float* __restrict__ W,
                                                     const float* __restrict__ bias,
                                                     float* __restrict__ out) {
    __shared__ unsigned int bitmap[BMW];
    __shared__ int toklist[T_TOK];
    __shared__ int cnt;

    const int b   = blockIdx.x;
    const int tid = threadIdx.x;

    for (int i = tid; i < BMW; i += 256) bitmap[i] = 0u;
    if (tid == 0) cnt = 0;
    __syncthreads();

    if (tid < T_TOK) {
        const int tok = text[tid * B_SZ + b];
        if (tok != PAD_TOK) {
            const unsigned mask = 1u << (tok & 31);
            const unsigned old  = atomicOr(&bitmap[tok >> 5], mask);
            if (!(old & mask)) {
                const int idx = atomicAdd(&cnt, 1);
                toklist[idx] = tok;
            }
        }
    }
    __syncthreads();

    const int n = cnt;
    float acc0 = bias[tid];
    float acc1 = bias[tid + 256];
    for (int i = 0; i < n; ++i) {
        const int tok = toklist[i];
        acc0 += W[(size_t)tid * V_SZ + tok];
        acc1 += W[(size_t)(tid + 256) * V_SZ + tok];
    }
    out[b * L_SZ + tid] = acc0;
    out[b * L_SZ + tid + 256] = acc1;
}

extern "C" void kernel_launch(void* const* d_in, const int* in_sizes, int n_in,
                              void* d_out, int out_size, void* d_ws, size_t ws_size,
                              hipStream_t stream) {
    const int*   text = (const int*)d_in[0];    // [T, B]
    const float* W    = (const float*)d_in[1];  // [L, V]
    const float* bias = (const float*)d_in[2];  // [L]
    float* out = (float*)d_out;                 // [B, L]

    const size_t need = (size_t)V_SZ * L_SZ * sizeof(__half);  // 51.2 MB
    if (ws_size >= need) {
        __half* Wt = (__half*)d_ws;             // [V, L] f16
        dim3 tb(256);
        dim3 tg((V_SZ + TT_V - 1) / TT_V, L_SZ / TT_L);   // (391, 4)
        transpose_W_f16<<<tg, tb, 0, stream>>>(W, Wt);
        bow_gather_f16<<<B_SZ, 256, 0, stream>>>(text, (const __half2*)Wt, bias, out);
    } else {
        bow_gather_nt<<<B_SZ, 256, 0, stream>>>(text, W, bias, out);
    }
}

// Round 4
// 193.909 us; speedup vs baseline: 1.1477x; 1.0035x over previous
//
#include <hip/hip_runtime.h>
#include <hip/hip_fp16.h>

// text [T,B] int tokens, W [L,V] f32, b [L] f32, out [B,L] f32.
// Multi-hot BOW (dedup per row, skip PAD) @ linear layer.
#define T_TOK 200
#define B_SZ  1024
#define V_SZ  50000
#define L_SZ  512
#define PAD_TOK 1

#define BMW ((V_SZ + 31) / 32)   // bitmap words = 1563
#define TOK_PAD_MAX 224          // 200 rounded up to multiple of 32

// ---------------------------------------------------------------------------
// Transpose + downconvert: W [L, V] f32 -> Wt [V+1, L] f16.
// Row V_SZ is zeroed (dummy token for gather-loop padding).
// 128(v) x 128(l) tile in LDS, stride 136 halfs (272 B = 17*16 B: keeps 16 B
// alignment for float4 store-phase reads). Grid: (391, 4), block 256.
// ---------------------------------------------------------------------------
#define TT_V 128
#define TT_L 128
#define TT_S 136   // LDS row stride in halfs

__global__ __launch_bounds__(256) void transpose_W_f16(const float* __restrict__ W,
                                                       __half* __restrict__ Wt) {
    __shared__ __half tile[TT_V * TT_S];   // 34816 B
    const int tid = threadIdx.x;
    const int v0  = blockIdx.x * TT_V;
    const int l0  = blockIdx.y * TT_L;

    // Load phase: thread covers v-quad [4*(tid&31)..+3] at rows l0 + (tid>>5) + 8k.
    const int vq   = 4 * (tid & 31);
    const int lrow = tid >> 5;
#pragma unroll
    for (int k = 0; k < TT_L / 8; ++k) {
        const int lt = lrow + 8 * k;         // 0..127
        const size_t base = (size_t)(l0 + lt) * V_SZ + v0 + vq;
        float4 val;
        if (v0 + vq + 3 < V_SZ) {
            val = *(const float4*)&W[base];
        } else {
            val.x = (v0 + vq + 0 < V_SZ) ? W[base + 0] : 0.0f;
            val.y = (v0 + vq + 1 < V_SZ) ? W[base + 1] : 0.0f;
            val.z = (v0 + vq + 2 < V_SZ) ? W[base + 2] : 0.0f;
            val.w = (v0 + vq + 3 < V_SZ) ? W[base + 3] : 0.0f;
        }
        tile[(vq + 0) * TT_S + lt] = __float2half(val.x);
        tile[(vq + 1) * TT_S + lt] = __float2half(val.y);
        tile[(vq + 2) * TT_S + lt] = __float2half(val.z);
        tile[(vq + 3) * TT_S + lt] = __float2half(val.w);
    }
    __syncthreads();

    // Store phase: 16 threads per v-row, each writes 8 halfs (16 B) of THIS
    // block's l-slice [l0, l0+128). 256 threads cover 16 rows/iter, 8 iters.
    const int vrow = tid >> 4;            // 0..15
    const int col8 = (tid & 15) * 8;      // 0..120
#pragma unroll
    for (int k = 0; k < TT_V / 16; ++k) {
        const int v  = vrow + 16 * k;     // 0..127
        const int vg = v0 + v;
        if (vg <= V_SZ) {   // row V_SZ gets zeros (load-phase guard filled 0)
            const float4 h = *(const float4*)&tile[v * TT_S + col8];
            *(float4*)&Wt[(size_t)vg * L_SZ + l0 + col8] = h;
        }
    }
}

// ---------------------------------------------------------------------------
// One block per batch row. Dedup via LDS bitmap; pad token list to x32 with
// dummy token V_SZ (zero row). Token loop: wave g handles tokens == g (mod 4);
// each lane loads 16 B (8 halfs) of the 1 KB Wt row -> one coalesced 1 KB
// load per wave per token, 8 independent loads in flight per thread.
// 4-way cross-wave LDS reduction at the end (reuses bitmap storage).
// ---------------------------------------------------------------------------
__global__ __launch_bounds__(256) void bow_gather_f16(const int* __restrict__ text,
                                                      const __half* __restrict__ Wt,
                                                      const float* __restrict__ bias,
                                                      float* __restrict__ out) {
    __shared__ unsigned int bmred[2048];   // bitmap (1563 w), then red[4][512] f32
    __shared__ int toklist[TOK_PAD_MAX];
    __shared__ int cnt;

    const int b    = blockIdx.x;
    const int tid  = threadIdx.x;
    const int lane = tid & 63;
    const int g    = tid >> 6;

    for (int i = tid; i < BMW; i += 256) bmred[i] = 0u;
    if (tid == 0) cnt = 0;
    __syncthreads();

    if (tid < T_TOK) {
        const int tok = text[tid * B_SZ + b];
        if (tok != PAD_TOK) {
            const unsigned mask = 1u << (tok & 31);
            const unsigned old  = atomicOr(&bmred[tok >> 5], mask);
            if (!(old & mask)) {
                const int idx = atomicAdd(&cnt, 1);
                toklist[idx] = tok;
            }
        }
    }
    __syncthreads();

    const int n     = cnt;
    const int n_pad = (n + 31) & ~31;
    for (int i = n + tid; i < n_pad; i += 256) toklist[i] = V_SZ;  // zero row
    __syncthreads();

    const float4* __restrict__ Wt4 = (const float4*)Wt;  // 64 float4 per row
    float2 a0 = {0.f, 0.f}, a1 = {0.f, 0.f}, a2 = {0.f, 0.f}, a3 = {0.f, 0.f};

    for (int i = 0; i < n_pad; i += 32) {
        const int t0 = toklist[i + g +  0], t1 = toklist[i + g +  4];
        const int t2 = toklist[i + g +  8], t3 = toklist[i + g + 12];
        const int t4 = toklist[i + g + 16], t5 = toklist[i + g + 20];
        const int t6 = toklist[i + g + 24], t7 = toklist[i + g + 28];
        const float4 w0 = Wt4[t0 * 64 + lane];
        const float4 w1 = Wt4[t1 * 64 + lane];
        const float4 w2 = Wt4[t2 * 64 + lane];
        const float4 w3 = Wt4[t3 * 64 + lane];
        const float4 w4 = Wt4[t4 * 64 + lane];
        const float4 w5 = Wt4[t5 * 64 + lane];
        const float4 w6 = Wt4[t6 * 64 + lane];
        const float4 w7 = Wt4[t7 * 64 + lane];
#define ACC16(w)                                                         \
        {                                                                \
            const __half2* h = (const __half2*)&(w);                     \
            float2 f;                                                    \
            f = __half22float2(h[0]); a0.x += f.x; a0.y += f.y;          \
            f = __half22float2(h[1]); a1.x += f.x; a1.y += f.y;          \
            f = __half22float2(h[2]); a2.x += f.x; a2.y += f.y;          \
            f = __half22float2(h[3]); a3.x += f.x; a3.y += f.y;          \
        }
        ACC16(w0) ACC16(w1) ACC16(w2) ACC16(w3)
        ACC16(w4) ACC16(w5) ACC16(w6) ACC16(w7)
#undef ACC16
    }

    __syncthreads();   // bitmap dead; reuse bmred as red[4][512] f32
    float* red = (float*)bmred;
    {
        float2* r2 = (float2*)&red[g * 512 + lane * 8];
        r2[0] = a0; r2[1] = a1; r2[2] = a2; r2[3] = a3;
    }
    __syncthreads();

    // thread tid sums l = 2*tid, 2*tid+1 across the 4 wave-partials.
    const float2* r2 = (const float2*)red;
    float2 s = ((const float2*)bias)[tid];
    const float2 p0 = r2[0 * 256 + tid], p1 = r2[1 * 256 + tid];
    const float2 p2 = r2[2 * 256 + tid], p3 = r2[3 * 256 + tid];
    s.x += p0.x + p1.x + p2.x + p3.x;
    s.y += p0.y + p1.y + p2.y + p3.y;
    ((float2*)out)[b * 256 + tid] = s;
}

// ---------------------------------------------------------------------------
// Fallback if workspace too small: gather directly from W (uncoalesced, slow).
// ---------------------------------------------------------------------------
__global__ __launch_bounds__(256) void bow_gather_nt(const int* __restrict__ text,
                                                     const float* __restrict__ W,
                                                     const float* __restrict__ bias,
                                                     float* __restrict__ out) {
    __shared__ unsigned int bitmap[BMW];
    __shared__ int toklist[T_TOK];
    __shared__ int cnt;

    const int b   = blockIdx.x;
    const int tid = threadIdx.x;

    for (int i = tid; i < BMW; i += 256) bitmap[i] = 0u;
    if (tid == 0) cnt = 0;
    __syncthreads();

    if (tid < T_TOK) {
        const int tok = text[tid * B_SZ + b];
        if (tok != PAD_TOK) {
            const unsigned mask = 1u << (tok & 31);
            const unsigned old  = atomicOr(&bitmap[tok >> 5], mask);
            if (!(old & mask)) {
                const int idx = atomicAdd(&cnt, 1);
                toklist[idx] = tok;
            }
        }
    }
    __syncthreads();

    const int n = cnt;
    float acc0 = bias[tid];
    float acc1 = bias[tid + 256];
    for (int i = 0; i < n; ++i) {
        const int tok = toklist[i];
        acc0 += W[(size_t)tid * V_SZ + tok];
        acc1 += W[(size_t)(tid + 256) * V_SZ + tok];
    }
    out[b * L_SZ + tid] = acc0;
    out[b * L_SZ + tid + 256] = acc1;
}

extern "C" void kernel_launch(void* const* d_in, const int* in_sizes, int n_in,
                              void* d_out, int out_size, void* d_ws, size_t ws_size,
                              hipStream_t stream) {
    const int*   text = (const int*)d_in[0];    // [T, B]
    const float* W    = (const float*)d_in[1];  // [L, V]
    const float* bias = (const float*)d_in[2];  // [L]
    float* out = (float*)d_out;                 // [B, L]

    const size_t need = (size_t)(V_SZ + 1) * L_SZ * sizeof(__half);  // 51.2 MB
    if (ws_size >= need) {
        __half* Wt = (__half*)d_ws;             // [V+1, L] f16
        dim3 tb(256);
        dim3 tg((V_SZ + TT_V - 1) / TT_V, L_SZ / TT_L);   // (391, 4)
        transpose_W_f16<<<tg, tb, 0, stream>>>(W, Wt);
        bow_gather_f16<<<B_SZ, 256, 0, stream>>>(text, Wt, bias, out);
    } else {
        bow_gather_nt<<<B_SZ, 256, 0, stream>>>(text, W, bias, out);
    }
}